// Round 7
// baseline (111.534 us; speedup 1.0000x reference)
//
#include <hip/hip_runtime.h>
#include <math.h>

// Problem constants (B, C, H, W) = (16, 256, 64, 64), GROUPS=4, RATIO=2
#define B_   16
#define C_   256
#define H_   64
#define W_   64
#define G_   4
#define HO_  128
#define WO_  128
#define HW_  (H_ * W_)
#define HOWO_ (HO_ * WO_)

// ---------------------------------------------------------------------------
// Prep: wcomb[u][i2][40] for wave u (v=u&3, hi=u>>2), channel i=64v+32hi+i2:
//   [0..31]  = w_off[o][i]                     o = 0..31
//   [32..39] = w_scope[v][j][32*hi + i2]       j = 0..7
// ---------------------------------------------------------------------------
__global__ __launch_bounds__(256) void prep_kernel(
    const float* __restrict__ w_off,    // (32, 256)
    const float* __restrict__ w_scope,  // (4, 8, 64)
    float* __restrict__ wcomb)          // (8, 32, 40)
{
    const int k = blockIdx.x * 256 + threadIdx.x;   // 10240 total
    if (k >= 8 * 32 * 40) return;
    const int q  = k % 40;
    const int r  = k / 40;
    const int i2 = r & 31;
    const int u  = r >> 5;
    const int v  = u & 3;
    const int hi = u >> 2;
    const int i  = 64 * v + 32 * hi + i2;
    float val;
    if (q < 32) val = w_off[q * 256 + i];
    else        val = w_scope[v * 512 + (q - 32) * 64 + 32 * hi + i2];
    wcomb[k] = val;
}

// ---------------------------------------------------------------------------
// Conv kernel: 512 threads = 8 waves, one block per input row (b,h).
// Wave u (v=u&3, hi=u>>2) owns channels [64v+32hi, +32). All 32 x-loads are
// hoisted into registers (full MLP), then FMAs against uniform s_load
// weights. 2-round LDS reduction; wave v (hi=0) emits group-v coords.
// ---------------------------------------------------------------------------
__global__ __launch_bounds__(512) void conv_kernel(
    const float* __restrict__ x,        // (B, 256, 64, 64)
    const float* __restrict__ wcomb,    // (8, 32, 40)
    const float* __restrict__ b_off,    // (32,)
    const float* __restrict__ b_scope,  // (32,)
    float2* __restrict__ coords)        // (B, 4, 128, 128)
{
    __shared__ float4 red[8][8][64];    // [slot][chunk][pixel] 32 KB
    __shared__ float4 aux[8][64];       // scp partials; 8 KB

    const int tid = threadIdx.x;
    const int u   = __builtin_amdgcn_readfirstlane(tid >> 6);  // wave id
    const int w   = tid & 63;                                  // pixel in row
    const int v   = u & 3;              // group
    const int hi  = u >> 2;             // channel half
    const int h   = blockIdx.x & 63;
    const int b   = blockIdx.x >> 6;

    const float* xq = x + (size_t)b * C_ * HW_ +
                      (size_t)(64 * v + 32 * hi) * HW_ + h * W_ + w;
    const float* wt = wcomb + u * (32 * 40);

    // hoist all 32 channel loads -> 32 outstanding vmem ops per wave
    float xv[32];
#pragma unroll
    for (int i2 = 0; i2 < 32; ++i2) xv[i2] = xq[(size_t)i2 * HW_];

    float offp[32];
    float scp[8];
#pragma unroll
    for (int j = 0; j < 32; ++j) offp[j] = 0.f;
#pragma unroll
    for (int j = 0; j < 8; ++j) scp[j] = 0.f;

#pragma unroll
    for (int i2 = 0; i2 < 32; ++i2) {
        const float* wr = wt + i2 * 40;          // uniform -> s_load
#pragma unroll
        for (int j = 0; j < 32; ++j) offp[j] += xv[i2] * wr[j];
#pragma unroll
        for (int j = 0; j < 8; ++j)  scp[j] += xv[i2] * wr[32 + j];
    }

    // ---- round 1: high waves publish; low waves absorb pair partner ----
    if (hi) {
#pragma unroll
        for (int j = 0; j < 8; ++j)
            red[4 + v][j][w] = make_float4(offp[4 * j + 0], offp[4 * j + 1],
                                           offp[4 * j + 2], offp[4 * j + 3]);
        aux[2 * v + 0][w] = make_float4(scp[0], scp[1], scp[2], scp[3]);
        aux[2 * v + 1][w] = make_float4(scp[4], scp[5], scp[6], scp[7]);
    }
    __syncthreads();
    if (!hi) {
#pragma unroll
        for (int j = 0; j < 8; ++j) {
            const float4 p = red[4 + v][j][w];
            offp[4 * j + 0] += p.x; offp[4 * j + 1] += p.y;
            offp[4 * j + 2] += p.z; offp[4 * j + 3] += p.w;
        }
        const float4 s0 = aux[2 * v + 0][w];
        const float4 s1 = aux[2 * v + 1][w];
        scp[0] += s0.x; scp[1] += s0.y; scp[2] += s0.z; scp[3] += s0.w;
        scp[4] += s1.x; scp[5] += s1.y; scp[6] += s1.z; scp[7] += s1.w;
#pragma unroll
        for (int j = 0; j < 8; ++j)
            red[v][j][w] = make_float4(offp[4 * j + 0], offp[4 * j + 1],
                                       offp[4 * j + 2], offp[4 * j + 3]);
    }
    __syncthreads();
    if (!hi) {
        float4 a = make_float4(0.f, 0.f, 0.f, 0.f);
        float4 c = make_float4(0.f, 0.f, 0.f, 0.f);
#pragma unroll
        for (int tt = 0; tt < 4; ++tt) {
            const float4 pa = red[tt][2 * v + 0][w];
            const float4 pc = red[tt][2 * v + 1][w];
            a.x += pa.x; a.y += pa.y; a.z += pa.z; a.w += pa.w;
            c.x += pc.x; c.y += pc.y; c.z += pc.z; c.w += pc.w;
        }
        const float ao[8] = {a.x, a.y, a.z, a.w, c.x, c.y, c.z, c.w};
        float f[8];
#pragma unroll
        for (int j = 0; j < 8; ++j) {
            const float offv = ao[j] + b_off[8 * v + j];
            const float scv  = scp[j] + b_scope[8 * v + j];
            f[j] = offv * 0.5f / (1.f + expf(-scv));
        }
        // coords for group v, rows 2h+r1; lanes adjacent -> coalesced float4
#pragma unroll
        for (int r1 = 0; r1 < 2; ++r1) {
            const float hoF = (float)(2 * h + r1);
            float ix0 = ((float)(2 * w + 0) - 0.5f + f[2 * r1 + 0]) * 0.5f;
            float iy0 = (hoF - 0.5f + f[4 + 2 * r1 + 0]) * 0.5f;
            float ix1 = ((float)(2 * w + 1) - 0.5f + f[2 * r1 + 1]) * 0.5f;
            float iy1 = (hoF - 0.5f + f[4 + 2 * r1 + 1]) * 0.5f;
            ix0 = fminf(fmaxf(ix0, 0.f), (float)(W_ - 1));
            iy0 = fminf(fmaxf(iy0, 0.f), (float)(H_ - 1));
            ix1 = fminf(fmaxf(ix1, 0.f), (float)(W_ - 1));
            iy1 = fminf(fmaxf(iy1, 0.f), (float)(H_ - 1));
            float4* cw = (float4*)&coords[(((size_t)b * G_ + v) * HO_ +
                                           (2 * h + r1)) * WO_ + 2 * w];
            *cw = make_float4(ix0, iy0, ix1, iy1);
        }
    }
}

// ---------------------------------------------------------------------------
// Sample kernel (R0-proven mapping, 4096 blocks). One thread per
// (b, g, ho, wo); loops the group's 64 channels; nontemporal coalesced
// writes along wo (out is written once, never read -> keep caches for x).
// ---------------------------------------------------------------------------
__global__ __launch_bounds__(256) void sample_kernel(
    const float* __restrict__ x,        // (B, 256, 64, 64)
    const float2* __restrict__ coords,  // (B, 4, 128, 128)
    float* __restrict__ out)            // (B, 256, 128, 128)
{
    const int wo = threadIdx.x & 127;
    const int ho = (blockIdx.x << 1) + (threadIdx.x >> 7);
    const int g  = blockIdx.y;
    const int b  = blockIdx.z;

    const float2 c = coords[(((size_t)b * G_ + g) * HO_ + ho) * WO_ + wo];
    const float ix = c.x, iy = c.y;

    const float x0f = floorf(ix);
    const float y0f = floorf(iy);
    const float wx = ix - x0f;
    const float wy = iy - y0f;
    int x0 = (int)x0f;
    int y0 = (int)y0f;
    x0 = max(0, min(x0, W_ - 1));
    y0 = max(0, min(y0, H_ - 1));
    const int x1 = min(x0 + 1, W_ - 1);
    const int y1 = min(y0 + 1, H_ - 1);

    const float w00 = (1.f - wy) * (1.f - wx);
    const float w01 = (1.f - wy) * wx;
    const float w10 = wy * (1.f - wx);
    const float w11 = wy * wx;

    const int p00 = y0 * W_ + x0;
    const int p01 = y0 * W_ + x1;
    const int p10 = y1 * W_ + x0;
    const int p11 = y1 * W_ + x1;

    const float* xb = x + (size_t)b * C_ * HW_ + (size_t)g * HW_;
    float* ob = out + (size_t)b * C_ * HOWO_ + (size_t)g * HOWO_ +
                ho * WO_ + wo;

#pragma unroll 4
    for (int cc = 0; cc < 64; ++cc) {
        const float* pl = xb + (size_t)cc * 4 * HW_;
        const float v = pl[p00] * w00 + pl[p01] * w01 +
                        pl[p10] * w10 + pl[p11] * w11;
        __builtin_nontemporal_store(v, &ob[(size_t)cc * 4 * HOWO_]);
    }
}

// ---------------------------------------------------------------------------
extern "C" void kernel_launch(void* const* d_in, const int* in_sizes, int n_in,
                              void* d_out, int out_size, void* d_ws, size_t ws_size,
                              hipStream_t stream) {
    const float* x       = (const float*)d_in[0];
    const float* w_off   = (const float*)d_in[1];
    const float* b_off   = (const float*)d_in[2];
    const float* w_scope = (const float*)d_in[3];
    const float* b_scope = (const float*)d_in[4];
    float* out = (float*)d_out;

    float* wcomb = (float*)d_ws;                       // 8*32*40 = 40 KB
    float2* coords = (float2*)((char*)d_ws + 65536);   // 8 MiB

    prep_kernel<<<dim3(40), 256, 0, stream>>>(w_off, w_scope, wcomb);
    conv_kernel<<<dim3(B_ * H_), 512, 0, stream>>>(
        x, wcomb, b_off, b_scope, coords);
    sample_kernel<<<dim3(HO_ / 2, G_, B_), 256, 0, stream>>>(x, coords, out);
}

// Round 8
// 102.799 us; speedup vs baseline: 1.0850x; 1.0850x over previous
//
#include <hip/hip_runtime.h>
#include <math.h>

// Problem constants (B, C, H, W) = (16, 256, 64, 64), GROUPS=4, RATIO=2
#define B_   16
#define C_   256
#define H_   64
#define W_   64
#define G_   4
#define HO_  128
#define WO_  128
#define HW_  (H_ * W_)
#define HOWO_ (HO_ * WO_)

typedef float f2v __attribute__((ext_vector_type(2), aligned(4)));

// ---------------------------------------------------------------------------
// Prep: wcomb[u][i2][40] for wave u (v=u&3, hi=u>>2), channel i=64v+32hi+i2:
//   [0..31]  = w_off[o][i]                     o = 0..31
//   [32..39] = w_scope[v][j][32*hi + i2]       j = 0..7
// ---------------------------------------------------------------------------
__global__ __launch_bounds__(256) void prep_kernel(
    const float* __restrict__ w_off,    // (32, 256)
    const float* __restrict__ w_scope,  // (4, 8, 64)
    float* __restrict__ wcomb)          // (8, 32, 40)
{
    const int k = blockIdx.x * 256 + threadIdx.x;   // 10240 total
    if (k >= 8 * 32 * 40) return;
    const int q  = k % 40;
    const int r  = k / 40;
    const int i2 = r & 31;
    const int u  = r >> 5;
    const int v  = u & 3;
    const int hi = u >> 2;
    const int i  = 64 * v + 32 * hi + i2;
    float val;
    if (q < 32) val = w_off[q * 256 + i];
    else        val = w_scope[v * 512 + (q - 32) * 64 + 32 * hi + i2];
    wcomb[k] = val;
}

// ---------------------------------------------------------------------------
// Fused kernel, 512 threads = 8 waves, one block per input row (b,h).
// Conv: wave u accumulates its 32 channels for all 32 off outputs (+8 scope
// of group v over its half); uniform s_load weights; 2-round LDS reduction;
// low waves emit group-v coords as per-wo-pair float4s in LDS.
// Sample: thread (g, z, w2) produces the wo pair (2w2, 2w2+1) for row 2h+z,
// 64 channels: 4 float2 gathers + 1 dwordx2 store per channel (wo-paired,
// horizontal corners folded into one float2 via px/t trick).
// ---------------------------------------------------------------------------
__global__ __launch_bounds__(512, 6) void fused_kernel(
    const float* __restrict__ x,        // (B, 256, 64, 64)
    const float* __restrict__ wcomb,    // (8, 32, 40)
    const float* __restrict__ b_off,    // (32,)
    const float* __restrict__ b_scope,  // (32,)
    float* __restrict__ out)            // (B, 256, 128, 128)
{
    __shared__ float4 red[8][8][64];    // [slot][chunk][pixel] 32 KB
    __shared__ float4 aux[8][64];       // scp partials, then coords; 8 KB

    const int tid = threadIdx.x;
    const int u   = __builtin_amdgcn_readfirstlane(tid >> 6);  // wave id
    const int w   = tid & 63;                                  // pixel in row
    const int v   = u & 3;              // group
    const int hi  = u >> 2;             // channel half
    const int h   = blockIdx.x & 63;
    const int b   = blockIdx.x >> 6;

    const float* xq = x + (size_t)b * C_ * HW_ +
                      (size_t)(64 * v + 32 * hi) * HW_ + h * W_ + w;
    const float* wt = wcomb + u * (32 * 40);

    float offp[32];
    float scp[8];
#pragma unroll
    for (int j = 0; j < 32; ++j) offp[j] = 0.f;
#pragma unroll
    for (int j = 0; j < 8; ++j) scp[j] = 0.f;

#pragma unroll 4
    for (int i2 = 0; i2 < 32; ++i2) {
        const float xv = xq[(size_t)i2 * HW_];   // coalesced 256 B / wave
        const float* wr = wt + i2 * 40;          // uniform -> s_load
#pragma unroll
        for (int j = 0; j < 32; ++j) offp[j] += xv * wr[j];
#pragma unroll
        for (int j = 0; j < 8; ++j)  scp[j] += xv * wr[32 + j];
    }

    // ---- round 1: high waves publish; low waves absorb pair partner ----
    if (hi) {
#pragma unroll
        for (int j = 0; j < 8; ++j)
            red[4 + v][j][w] = make_float4(offp[4 * j + 0], offp[4 * j + 1],
                                           offp[4 * j + 2], offp[4 * j + 3]);
        aux[2 * v + 0][w] = make_float4(scp[0], scp[1], scp[2], scp[3]);
        aux[2 * v + 1][w] = make_float4(scp[4], scp[5], scp[6], scp[7]);
    }
    __syncthreads();
    if (!hi) {
#pragma unroll
        for (int j = 0; j < 8; ++j) {
            const float4 p = red[4 + v][j][w];
            offp[4 * j + 0] += p.x; offp[4 * j + 1] += p.y;
            offp[4 * j + 2] += p.z; offp[4 * j + 3] += p.w;
        }
        const float4 s0 = aux[2 * v + 0][w];
        const float4 s1 = aux[2 * v + 1][w];
        scp[0] += s0.x; scp[1] += s0.y; scp[2] += s0.z; scp[3] += s0.w;
        scp[4] += s1.x; scp[5] += s1.y; scp[6] += s1.z; scp[7] += s1.w;
        // round 2 publish
#pragma unroll
        for (int j = 0; j < 8; ++j)
            red[v][j][w] = make_float4(offp[4 * j + 0], offp[4 * j + 1],
                                       offp[4 * j + 2], offp[4 * j + 3]);
    }
    __syncthreads();
    if (!hi) {
        float4 a = make_float4(0.f, 0.f, 0.f, 0.f);
        float4 c = make_float4(0.f, 0.f, 0.f, 0.f);
#pragma unroll
        for (int tt = 0; tt < 4; ++tt) {
            const float4 pa = red[tt][2 * v + 0][w];
            const float4 pc = red[tt][2 * v + 1][w];
            a.x += pa.x; a.y += pa.y; a.z += pa.z; a.w += pa.w;
            c.x += pc.x; c.y += pc.y; c.z += pc.z; c.w += pc.w;
        }
        const float ao[8] = {a.x, a.y, a.z, a.w, c.x, c.y, c.z, c.w};
        float f[8];
#pragma unroll
        for (int j = 0; j < 8; ++j) {
            const float offv = ao[j] + b_off[8 * v + j];
            const float scv  = scp[j] + b_scope[8 * v + j];
            f[j] = offv * 0.5f / (1.f + expf(-scv));
        }
        // coords for group v: aux[2v+r1][w] = (ix0,iy0,ix1,iy1) for wo=2w,2w+1
#pragma unroll
        for (int r1 = 0; r1 < 2; ++r1) {
            const float hoF = (float)(2 * h + r1);
            float ix0 = ((float)(2 * w + 0) - 0.5f + f[2 * r1 + 0]) * 0.5f;
            float iy0 = (hoF - 0.5f + f[4 + 2 * r1 + 0]) * 0.5f;
            float ix1 = ((float)(2 * w + 1) - 0.5f + f[2 * r1 + 1]) * 0.5f;
            float iy1 = (hoF - 0.5f + f[4 + 2 * r1 + 1]) * 0.5f;
            ix0 = fminf(fmaxf(ix0, 0.f), (float)(W_ - 1));
            iy0 = fminf(fmaxf(iy0, 0.f), (float)(H_ - 1));
            ix1 = fminf(fmaxf(ix1, 0.f), (float)(W_ - 1));
            iy1 = fminf(fmaxf(iy1, 0.f), (float)(H_ - 1));
            aux[2 * v + r1][w] = make_float4(ix0, iy0, ix1, iy1);
        }
    }
    __syncthreads();

    // ---------------- phase 2: bilinear sampling, wo-paired --------------
    const int w2 = tid & 63;            // wo pair index -> wo = 2w2, 2w2+1
    const int z  = (tid >> 6) & 1;      // output row parity
    const int g  = tid >> 7;            // group 0..3
    const int ho = 2 * h + z;

    const float4 cq = aux[2 * g + z][w2];   // (ix0, iy0, ix1, iy1)

    float t0, wy0, t1, wy1;
    int oT0, oB0, oT1, oB1;
    {
        const float x0f = floorf(cq.x);
        const float y0f = floorf(cq.y);
        const int x0 = (int)x0f;
        const int y0 = (int)y0f;
        const int px = min(x0, W_ - 2);
        const int yb = min(y0 + 1, H_ - 1);
        t0  = (cq.x - x0f) + (float)(x0 - px);   // t=1 selects right elem at border
        wy0 = cq.y - y0f;
        oT0 = y0 * W_ + px;
        oB0 = yb * W_ + px;
    }
    {
        const float x0f = floorf(cq.z);
        const float y0f = floorf(cq.w);
        const int x0 = (int)x0f;
        const int y0 = (int)y0f;
        const int px = min(x0, W_ - 2);
        const int yb = min(y0 + 1, H_ - 1);
        t1  = (cq.z - x0f) + (float)(x0 - px);
        wy1 = cq.w - y0f;
        oT1 = y0 * W_ + px;
        oB1 = yb * W_ + px;
    }

    const float* xb = x + (size_t)b * C_ * HW_ + (size_t)g * HW_;
    float* ob = out + (size_t)b * C_ * HOWO_ + (size_t)g * HOWO_ +
                ho * WO_ + 2 * w2;

#pragma unroll 4
    for (int cc = 0; cc < 64; ++cc) {
        const float* pl = xb + (size_t)cc * 4 * HW_;
        const f2v a0 = *(const f2v*)(pl + oT0);
        const f2v b0 = *(const f2v*)(pl + oB0);
        const f2v a1 = *(const f2v*)(pl + oT1);
        const f2v b1 = *(const f2v*)(pl + oB1);
        const float top0 = a0.x + t0 * (a0.y - a0.x);
        const float bot0 = b0.x + t0 * (b0.y - b0.x);
        const float v0 = top0 + wy0 * (bot0 - top0);
        const float top1 = a1.x + t1 * (a1.y - a1.x);
        const float bot1 = b1.x + t1 * (b1.y - b1.x);
        const float v1 = top1 + wy1 * (bot1 - top1);
        *(float2*)(&ob[(size_t)cc * 4 * HOWO_]) = make_float2(v0, v1);
    }
}

// ---------------------------------------------------------------------------
extern "C" void kernel_launch(void* const* d_in, const int* in_sizes, int n_in,
                              void* d_out, int out_size, void* d_ws, size_t ws_size,
                              hipStream_t stream) {
    const float* x       = (const float*)d_in[0];
    const float* w_off   = (const float*)d_in[1];
    const float* b_off   = (const float*)d_in[2];
    const float* w_scope = (const float*)d_in[3];
    const float* b_scope = (const float*)d_in[4];
    float* out = (float*)d_out;
    float* wcomb = (float*)d_ws;   // 8*32*40 floats = 40 KB

    prep_kernel<<<dim3(40), 256, 0, stream>>>(w_off, w_scope, wcomb);
    fused_kernel<<<dim3(B_ * H_), 512, 0, stream>>>(
        x, wcomb, b_off, b_scope, out);
}

// Round 9
// 93.406 us; speedup vs baseline: 1.1941x; 1.1006x over previous
//
#include <hip/hip_runtime.h>
#include <math.h>

// Problem constants (B, C, H, W) = (16, 256, 64, 64), GROUPS=4, RATIO=2
#define B_   16
#define C_   256
#define H_   64
#define W_   64
#define G_   4
#define HO_  128
#define WO_  128
#define HW_  (H_ * W_)
#define HOWO_ (HO_ * WO_)

// Weights in constant address space -> uniform accesses compile to s_load
// (SMEM pipe, broadcast-natural, zero TCP/L1 pressure).
__constant__ float wconst[8 * 32 * 40];   // 40 KB

// ---------------------------------------------------------------------------
// Prep: wcomb[u][i2][40] for wave u (v=u&3, hi=u>>2), channel i=64v+32hi+i2:
//   [0..31]  = w_off[o][i]                     o = 0..31
//   [32..39] = w_scope[v][j][32*hi + i2]       j = 0..7
// Written into wconst's backing store (pointer obtained on host).
// ---------------------------------------------------------------------------
__global__ __launch_bounds__(256) void prep_kernel(
    const float* __restrict__ w_off,    // (32, 256)
    const float* __restrict__ w_scope,  // (4, 8, 64)
    float* __restrict__ wout)           // = wconst backing store
{
    const int k = blockIdx.x * 256 + threadIdx.x;   // 10240 total
    if (k >= 8 * 32 * 40) return;
    const int q  = k % 40;
    const int r  = k / 40;
    const int i2 = r & 31;
    const int u  = r >> 5;
    const int v  = u & 3;
    const int hi = u >> 2;
    const int i  = 64 * v + 32 * hi + i2;
    float val;
    if (q < 32) val = w_off[q * 256 + i];
    else        val = w_scope[v * 512 + (q - 32) * 64 + 32 * hi + i2];
    wout[k] = val;
}

// ---------------------------------------------------------------------------
// Fused kernel (R5 structure verbatim; only the weight transport changed).
// 512 threads = 8 waves, one block per input row (b,h).
// Conv: wave u accumulates its 32 channels for all 32 off outputs (+8 scope
// of group v over its half); weights via s_load from wconst; 2-round LDS
// reduction; low waves emit group-v coords into LDS.
// Sample: thread (g, z, wo) does 2 groups x 64 channels of bilinear taps.
// ---------------------------------------------------------------------------
__global__ __launch_bounds__(512, 6) void fused_kernel(
    const float* __restrict__ x,        // (B, 256, 64, 64)
    const float* __restrict__ b_off,    // (32,)
    const float* __restrict__ b_scope,  // (32,)
    float* __restrict__ out)            // (B, 256, 128, 128)
{
    __shared__ float4 red[8][8][64];    // [slot][chunk][pixel] 32 KB
    __shared__ float4 aux[8][64];       // scp partials, then coords; 8 KB

    const int tid = threadIdx.x;
    const int u   = __builtin_amdgcn_readfirstlane(tid >> 6);  // wave id
    const int w   = tid & 63;                                  // pixel in row
    const int v   = u & 3;              // group
    const int hi  = u >> 2;             // channel half
    const int h   = blockIdx.x & 63;
    const int b   = blockIdx.x >> 6;

    const float* xq = x + (size_t)b * C_ * HW_ +
                      (size_t)(64 * v + 32 * hi) * HW_ + h * W_ + w;
    const int wbase0 = u * (32 * 40);   // uniform

    float offp[32];
    float scp[8];
#pragma unroll
    for (int j = 0; j < 32; ++j) offp[j] = 0.f;
#pragma unroll
    for (int j = 0; j < 8; ++j) scp[j] = 0.f;

#pragma unroll 4
    for (int i2 = 0; i2 < 32; ++i2) {
        const float xv = xq[(size_t)i2 * HW_];   // coalesced 256 B / wave
        const int wb = wbase0 + i2 * 40;         // uniform -> s_load from AS4
#pragma unroll
        for (int j = 0; j < 32; ++j) offp[j] += xv * wconst[wb + j];
#pragma unroll
        for (int j = 0; j < 8; ++j)  scp[j] += xv * wconst[wb + 32 + j];
    }

    // ---- round 1: high waves publish; low waves absorb pair partner ----
    if (hi) {
#pragma unroll
        for (int j = 0; j < 8; ++j)
            red[4 + v][j][w] = make_float4(offp[4 * j + 0], offp[4 * j + 1],
                                           offp[4 * j + 2], offp[4 * j + 3]);
        aux[2 * v + 0][w] = make_float4(scp[0], scp[1], scp[2], scp[3]);
        aux[2 * v + 1][w] = make_float4(scp[4], scp[5], scp[6], scp[7]);
    }
    __syncthreads();
    if (!hi) {
#pragma unroll
        for (int j = 0; j < 8; ++j) {
            const float4 p = red[4 + v][j][w];
            offp[4 * j + 0] += p.x; offp[4 * j + 1] += p.y;
            offp[4 * j + 2] += p.z; offp[4 * j + 3] += p.w;
        }
        const float4 s0 = aux[2 * v + 0][w];
        const float4 s1 = aux[2 * v + 1][w];
        scp[0] += s0.x; scp[1] += s0.y; scp[2] += s0.z; scp[3] += s0.w;
        scp[4] += s1.x; scp[5] += s1.y; scp[6] += s1.z; scp[7] += s1.w;
        // round 2 publish
#pragma unroll
        for (int j = 0; j < 8; ++j)
            red[v][j][w] = make_float4(offp[4 * j + 0], offp[4 * j + 1],
                                       offp[4 * j + 2], offp[4 * j + 3]);
    }
    __syncthreads();
    if (!hi) {
        float4 a = make_float4(0.f, 0.f, 0.f, 0.f);
        float4 c = make_float4(0.f, 0.f, 0.f, 0.f);
#pragma unroll
        for (int tt = 0; tt < 4; ++tt) {
            const float4 pa = red[tt][2 * v + 0][w];
            const float4 pc = red[tt][2 * v + 1][w];
            a.x += pa.x; a.y += pa.y; a.z += pa.z; a.w += pa.w;
            c.x += pc.x; c.y += pc.y; c.z += pc.z; c.w += pc.w;
        }
        const float ao[8] = {a.x, a.y, a.z, a.w, c.x, c.y, c.z, c.w};
        float f[8];
#pragma unroll
        for (int j = 0; j < 8; ++j) {
            const float offv = ao[j] + b_off[8 * v + j];
            const float scv  = scp[j] + b_scope[8 * v + j];
            f[j] = offv * 0.5f / (1.f + expf(-scv));
        }
        // coords for group v: aux[2v+r1][w] = (ix0,iy0,ix1,iy1) for wo=2w,2w+1
#pragma unroll
        for (int r1 = 0; r1 < 2; ++r1) {
            const float hoF = (float)(2 * h + r1);
            float ix0 = ((float)(2 * w + 0) - 0.5f + f[2 * r1 + 0]) * 0.5f;
            float iy0 = (hoF - 0.5f + f[4 + 2 * r1 + 0]) * 0.5f;
            float ix1 = ((float)(2 * w + 1) - 0.5f + f[2 * r1 + 1]) * 0.5f;
            float iy1 = (hoF - 0.5f + f[4 + 2 * r1 + 1]) * 0.5f;
            ix0 = fminf(fmaxf(ix0, 0.f), (float)(W_ - 1));
            iy0 = fminf(fmaxf(iy0, 0.f), (float)(H_ - 1));
            ix1 = fminf(fmaxf(ix1, 0.f), (float)(W_ - 1));
            iy1 = fminf(fmaxf(iy1, 0.f), (float)(H_ - 1));
            aux[2 * v + r1][w] = make_float4(ix0, iy0, ix1, iy1);
        }
    }
    __syncthreads();

    // ---------------- phase 2: bilinear sampling (R5 verbatim) ----------
    const int wo = tid & 127;
    const int z  = (tid >> 7) & 1;
    const int gh = tid >> 8;            // group half
    const int ho = 2 * h + z;

    const float2* cbase = (const float2*)&aux[0][0];
    const float* xb0 = x + (size_t)b * C_ * HW_;
    float* ob0 = out + (size_t)b * C_ * HOWO_ + ho * WO_ + wo;

#pragma unroll
    for (int gg = 0; gg < 2; ++gg) {
        const int g = 2 * gh + gg;
        const float2 c = cbase[(g * 2 + z) * 128 + wo];
        const float ix = c.x, iy = c.y;

        const float x0f = floorf(ix);
        const float y0f = floorf(iy);
        const float wx = ix - x0f;
        const float wy = iy - y0f;
        int x0 = (int)x0f;
        int y0 = (int)y0f;
        x0 = max(0, min(x0, W_ - 1));
        y0 = max(0, min(y0, H_ - 1));
        const int x1 = min(x0 + 1, W_ - 1);
        const int y1 = min(y0 + 1, H_ - 1);

        const float w00 = (1.f - wy) * (1.f - wx);
        const float w01 = (1.f - wy) * wx;
        const float w10 = wy * (1.f - wx);
        const float w11 = wy * wx;

        const int p00 = y0 * W_ + x0;
        const int p01 = y0 * W_ + x1;
        const int p10 = y1 * W_ + x0;
        const int p11 = y1 * W_ + x1;

        const float* xb = xb0 + (size_t)g * HW_;
        float* ob = ob0 + (size_t)g * HOWO_;

#pragma unroll 4
        for (int cc = 0; cc < 64; ++cc) {
            const float* pl = xb + (size_t)cc * 4 * HW_;
            const float val = pl[p00] * w00 + pl[p01] * w01 +
                              pl[p10] * w10 + pl[p11] * w11;
            ob[(size_t)cc * 4 * HOWO_] = val;
        }
    }
}

// ---------------------------------------------------------------------------
extern "C" void kernel_launch(void* const* d_in, const int* in_sizes, int n_in,
                              void* d_out, int out_size, void* d_ws, size_t ws_size,
                              hipStream_t stream) {
    const float* x       = (const float*)d_in[0];
    const float* w_off   = (const float*)d_in[1];
    const float* b_off   = (const float*)d_in[2];
    const float* w_scope = (const float*)d_in[3];
    const float* b_scope = (const float*)d_in[4];
    float* out = (float*)d_out;

    // Backing store of the __constant__ array (runtime query, capture-safe:
    // no stream interaction, no allocation).
    void* wsym = nullptr;
    (void)hipGetSymbolAddress(&wsym, HIP_SYMBOL(wconst));

    prep_kernel<<<dim3(40), 256, 0, stream>>>(w_off, w_scope, (float*)wsym);
    fused_kernel<<<dim3(B_ * H_), 512, 0, stream>>>(x, b_off, b_scope, out);
}

// Round 10
// 84.356 us; speedup vs baseline: 1.3222x; 1.1073x over previous
//
#include <hip/hip_runtime.h>
#include <math.h>

// Problem constants (B, C, H, W) = (16, 256, 64, 64), GROUPS=4, RATIO=2
#define B_   16
#define C_   256
#define H_   64
#define W_   64
#define G_   4
#define HO_  128
#define WO_  128
#define HW_  (H_ * W_)
#define HOWO_ (HO_ * WO_)

// Weights in constant address space -> uniform accesses compile to s_load.
__constant__ float wconst[8 * 32 * 40];   // 40 KB

// ---------------------------------------------------------------------------
// Prep: wcomb[u][i2][40] for wave u (v=u&3, hi=u>>2), channel i=64v+32hi+i2:
//   [0..31]  = w_off[o][i]                     o = 0..31
//   [32..39] = w_scope[v][j][32*hi + i2]       j = 0..7
// ---------------------------------------------------------------------------
__global__ __launch_bounds__(256) void prep_kernel(
    const float* __restrict__ w_off,    // (32, 256)
    const float* __restrict__ w_scope,  // (4, 8, 64)
    float* __restrict__ wout)           // = wconst backing store
{
    const int k = blockIdx.x * 256 + threadIdx.x;   // 10240 total
    if (k >= 8 * 32 * 40) return;
    const int q  = k % 40;
    const int r  = k / 40;
    const int i2 = r & 31;
    const int u  = r >> 5;
    const int v  = u & 3;
    const int hi = u >> 2;
    const int i  = 64 * v + 32 * hi + i2;
    float val;
    if (q < 32) val = w_off[q * 256 + i];
    else        val = w_scope[v * 512 + (q - 32) * 64 + 32 * hi + i2];
    wout[k] = val;
}

// ---------------------------------------------------------------------------
// Fused kernel (R8 structure verbatim + XCD-bijective block swizzle).
// Grid = 1024 = full-chip co-residency; swizzle gives XCD k the blocks with
// b in {2k, 2k+1} and ALL h -> h-adjacent x-slab sharing lands in one L2.
// ---------------------------------------------------------------------------
__global__ __launch_bounds__(512, 6) void fused_kernel(
    const float* __restrict__ x,        // (B, 256, 64, 64)
    const float* __restrict__ b_off,    // (32,)
    const float* __restrict__ b_scope,  // (32,)
    float* __restrict__ out)            // (B, 256, 128, 128)
{
    __shared__ float4 red[8][8][64];    // [slot][chunk][pixel] 32 KB
    __shared__ float4 aux[8][64];       // scp partials, then coords; 8 KB

    const int tid = threadIdx.x;
    const int u   = __builtin_amdgcn_readfirstlane(tid >> 6);  // wave id
    const int w   = tid & 63;                                  // pixel in row

    // XCD-bijective swizzle: original bid n runs on XCD n%8 (round-robin);
    // give that XCD the logical tile (n%8)*128 + n/8 so each XCD owns a
    // contiguous 128-tile chunk (= 2 full b, all h). 1024 % 8 == 0.
    const int bid = ((blockIdx.x & 7) << 7) | (blockIdx.x >> 3);
    const int h   = bid & 63;
    const int b   = bid >> 6;

    const int v   = u & 3;              // group
    const int hi  = u >> 2;             // channel half

    const float* xq = x + (size_t)b * C_ * HW_ +
                      (size_t)(64 * v + 32 * hi) * HW_ + h * W_ + w;
    const int wbase0 = u * (32 * 40);   // uniform

    float offp[32];
    float scp[8];
#pragma unroll
    for (int j = 0; j < 32; ++j) offp[j] = 0.f;
#pragma unroll
    for (int j = 0; j < 8; ++j) scp[j] = 0.f;

#pragma unroll 4
    for (int i2 = 0; i2 < 32; ++i2) {
        const float xv = xq[(size_t)i2 * HW_];   // coalesced 256 B / wave
        const int wb = wbase0 + i2 * 40;         // uniform -> s_load from AS4
#pragma unroll
        for (int j = 0; j < 32; ++j) offp[j] += xv * wconst[wb + j];
#pragma unroll
        for (int j = 0; j < 8; ++j)  scp[j] += xv * wconst[wb + 32 + j];
    }

    // ---- round 1: high waves publish; low waves absorb pair partner ----
    if (hi) {
#pragma unroll
        for (int j = 0; j < 8; ++j)
            red[4 + v][j][w] = make_float4(offp[4 * j + 0], offp[4 * j + 1],
                                           offp[4 * j + 2], offp[4 * j + 3]);
        aux[2 * v + 0][w] = make_float4(scp[0], scp[1], scp[2], scp[3]);
        aux[2 * v + 1][w] = make_float4(scp[4], scp[5], scp[6], scp[7]);
    }
    __syncthreads();
    if (!hi) {
#pragma unroll
        for (int j = 0; j < 8; ++j) {
            const float4 p = red[4 + v][j][w];
            offp[4 * j + 0] += p.x; offp[4 * j + 1] += p.y;
            offp[4 * j + 2] += p.z; offp[4 * j + 3] += p.w;
        }
        const float4 s0 = aux[2 * v + 0][w];
        const float4 s1 = aux[2 * v + 1][w];
        scp[0] += s0.x; scp[1] += s0.y; scp[2] += s0.z; scp[3] += s0.w;
        scp[4] += s1.x; scp[5] += s1.y; scp[6] += s1.z; scp[7] += s1.w;
        // round 2 publish
#pragma unroll
        for (int j = 0; j < 8; ++j)
            red[v][j][w] = make_float4(offp[4 * j + 0], offp[4 * j + 1],
                                       offp[4 * j + 2], offp[4 * j + 3]);
    }
    __syncthreads();
    if (!hi) {
        float4 a = make_float4(0.f, 0.f, 0.f, 0.f);
        float4 c = make_float4(0.f, 0.f, 0.f, 0.f);
#pragma unroll
        for (int tt = 0; tt < 4; ++tt) {
            const float4 pa = red[tt][2 * v + 0][w];
            const float4 pc = red[tt][2 * v + 1][w];
            a.x += pa.x; a.y += pa.y; a.z += pa.z; a.w += pa.w;
            c.x += pc.x; c.y += pc.y; c.z += pc.z; c.w += pc.w;
        }
        const float ao[8] = {a.x, a.y, a.z, a.w, c.x, c.y, c.z, c.w};
        float f[8];
#pragma unroll
        for (int j = 0; j < 8; ++j) {
            const float offv = ao[j] + b_off[8 * v + j];
            const float scv  = scp[j] + b_scope[8 * v + j];
            f[j] = offv * 0.5f / (1.f + expf(-scv));
        }
        // coords for group v: aux[2v+r1][w] = (ix0,iy0,ix1,iy1) for wo=2w,2w+1
#pragma unroll
        for (int r1 = 0; r1 < 2; ++r1) {
            const float hoF = (float)(2 * h + r1);
            float ix0 = ((float)(2 * w + 0) - 0.5f + f[2 * r1 + 0]) * 0.5f;
            float iy0 = (hoF - 0.5f + f[4 + 2 * r1 + 0]) * 0.5f;
            float ix1 = ((float)(2 * w + 1) - 0.5f + f[2 * r1 + 1]) * 0.5f;
            float iy1 = (hoF - 0.5f + f[4 + 2 * r1 + 1]) * 0.5f;
            ix0 = fminf(fmaxf(ix0, 0.f), (float)(W_ - 1));
            iy0 = fminf(fmaxf(iy0, 0.f), (float)(H_ - 1));
            ix1 = fminf(fmaxf(ix1, 0.f), (float)(W_ - 1));
            iy1 = fminf(fmaxf(iy1, 0.f), (float)(H_ - 1));
            aux[2 * v + r1][w] = make_float4(ix0, iy0, ix1, iy1);
        }
    }
    __syncthreads();

    // ---------------- phase 2: bilinear sampling ----------------
    const int wo = tid & 127;
    const int z  = (tid >> 7) & 1;
    const int gh = tid >> 8;            // group half
    const int ho = 2 * h + z;

    const float2* cbase = (const float2*)&aux[0][0];
    const float* xb0 = x + (size_t)b * C_ * HW_;
    float* ob0 = out + (size_t)b * C_ * HOWO_ + ho * WO_ + wo;

#pragma unroll
    for (int gg = 0; gg < 2; ++gg) {
        const int g = 2 * gh + gg;
        const float2 c = cbase[(g * 2 + z) * 128 + wo];
        const float ix = c.x, iy = c.y;

        const float x0f = floorf(ix);
        const float y0f = floorf(iy);
        const float wx = ix - x0f;
        const float wy = iy - y0f;
        int x0 = (int)x0f;
        int y0 = (int)y0f;
        x0 = max(0, min(x0, W_ - 1));
        y0 = max(0, min(y0, H_ - 1));
        const int x1 = min(x0 + 1, W_ - 1);
        const int y1 = min(y0 + 1, H_ - 1);

        const float w00 = (1.f - wy) * (1.f - wx);
        const float w01 = (1.f - wy) * wx;
        const float w10 = wy * (1.f - wx);
        const float w11 = wy * wx;

        const int p00 = y0 * W_ + x0;
        const int p01 = y0 * W_ + x1;
        const int p10 = y1 * W_ + x0;
        const int p11 = y1 * W_ + x1;

        const float* xb = xb0 + (size_t)g * HW_;
        float* ob = ob0 + (size_t)g * HOWO_;

#pragma unroll 4
        for (int cc = 0; cc < 64; ++cc) {
            const float* pl = xb + (size_t)cc * 4 * HW_;
            const float val = pl[p00] * w00 + pl[p01] * w01 +
                              pl[p10] * w10 + pl[p11] * w11;
            ob[(size_t)cc * 4 * HOWO_] = val;
        }
    }
}

// ---------------------------------------------------------------------------
extern "C" void kernel_launch(void* const* d_in, const int* in_sizes, int n_in,
                              void* d_out, int out_size, void* d_ws, size_t ws_size,
                              hipStream_t stream) {
    const float* x       = (const float*)d_in[0];
    const float* w_off   = (const float*)d_in[1];
    const float* b_off   = (const float*)d_in[2];
    const float* w_scope = (const float*)d_in[3];
    const float* b_scope = (const float*)d_in[4];
    float* out = (float*)d_out;

    void* wsym = nullptr;
    (void)hipGetSymbolAddress(&wsym, HIP_SYMBOL(wconst));

    prep_kernel<<<dim3(40), 256, 0, stream>>>(w_off, w_scope, (float*)wsym);
    fused_kernel<<<dim3(B_ * H_), 512, 0, stream>>>(x, b_off, b_scope, out);
}